// Round 1
// baseline (94.219 us; speedup 1.0000x reference)
//
#include <hip/hip_runtime.h>

// SpikeFP32Embedding: out[t, :, :] = weight_pulse[token_ids[t], :, :]
// Row = 128*32 = 4096 float32 = 16 KiB = 1024 float4.
// One 256-thread block per token, 4 float4 copies per thread, coalesced.

static constexpr int ROW_F4 = 4096 / 4;   // 1024 float4 per row
static constexpr int BLOCK   = 256;

__global__ __launch_bounds__(BLOCK) void spike_embed_gather(
    const int* __restrict__ tok,
    const float4* __restrict__ w,
    float4* __restrict__ out) {
    const int t = blockIdx.x;                       // token slot 0..n_tok-1
    const long long row = (long long)tok[t];        // padded table: row < 32768
    const float4* __restrict__ src = w + row * (long long)ROW_F4;
    float4* __restrict__ dst = out + (long long)t * (long long)ROW_F4;
#pragma unroll
    for (int i = 0; i < ROW_F4 / BLOCK; ++i) {      // 4 iterations
        const int idx = threadIdx.x + i * BLOCK;
        dst[idx] = src[idx];
    }
}

extern "C" void kernel_launch(void* const* d_in, const int* in_sizes, int n_in,
                              void* d_out, int out_size, void* d_ws, size_t ws_size,
                              hipStream_t stream) {
    const int* tok   = (const int*)d_in[0];         // token_ids, flat [8*2048]
    const float4* w  = (const float4*)d_in[1];      // weight_pulse [32768,128,32] f32
    float4* out      = (float4*)d_out;              // [n_tok,128,32] f32

    const int n_tok = in_sizes[0];                  // 16384
    spike_embed_gather<<<n_tok, BLOCK, 0, stream>>>(tok, w, out);
}

// Round 3
// 82.379 us; speedup vs baseline: 1.1437x; 1.1437x over previous
//
#include <hip/hip_runtime.h>

// SpikeFP32Embedding: out[t, :, :] = weight_pulse[token_ids[t], :, :]
// Row = 128*32 = 4096 float32 = 16 KiB = 1024 x 16B vectors.
// One 256-thread block per token; 4 x 16B per thread.
// Loads batched first (MLP=4), then nontemporal stores so the 256 MiB
// output stream doesn't evict weight rows from L2/L3 (repeat-token hits).
// NOTE: __builtin_nontemporal_store requires a NATIVE vector type, not
// HIP_vector_type<float,4> -- use ext_vector_type(4).

typedef float f32x4 __attribute__((ext_vector_type(4)));

static constexpr int ROW_V = 1024;   // 16B vectors per row
static constexpr int BLOCK = 256;

__global__ __launch_bounds__(BLOCK) void spike_embed_gather(
    const int* __restrict__ tok,
    const f32x4* __restrict__ w,
    f32x4* __restrict__ out) {
    const int t = blockIdx.x;
    const long long row = (long long)tok[t];       // wave-uniform -> s_load
    const f32x4* __restrict__ src = w + row * (long long)ROW_V;
    f32x4* __restrict__ dst = out + (long long)t * (long long)ROW_V;

    const int i0 = threadIdx.x;
    // Issue all 4 loads before any store: 4 outstanding vmem loads/thread.
    const f32x4 r0 = src[i0];
    const f32x4 r1 = src[i0 + BLOCK];
    const f32x4 r2 = src[i0 + 2 * BLOCK];
    const f32x4 r3 = src[i0 + 3 * BLOCK];
    __builtin_nontemporal_store(r0, &dst[i0]);
    __builtin_nontemporal_store(r1, &dst[i0 + BLOCK]);
    __builtin_nontemporal_store(r2, &dst[i0 + 2 * BLOCK]);
    __builtin_nontemporal_store(r3, &dst[i0 + 3 * BLOCK]);
}

extern "C" void kernel_launch(void* const* d_in, const int* in_sizes, int n_in,
                              void* d_out, int out_size, void* d_ws, size_t ws_size,
                              hipStream_t stream) {
    const int* tok   = (const int*)d_in[0];         // token_ids, flat [8*2048]
    const f32x4* w   = (const f32x4*)d_in[1];       // weight_pulse [32768,128,32] f32
    f32x4* out       = (f32x4*)d_out;               // [n_tok,128,32] f32

    const int n_tok = in_sizes[0];                  // 16384
    spike_embed_gather<<<n_tok, BLOCK, 0, stream>>>(tok, w, out);
}